// Round 9
// baseline (629.797 us; speedup 1.0000x reference)
//
#include <hip/hip_runtime.h>
#include <hip/hip_fp16.h>
#include <math.h>

// Problem constants (from reference)
#define BS    8
#define NE    4800
#define NN    4981
#define CIN   3
#define HD    128      // H
#define DBLK  6        // D processor blocks
#define NEDGE 153600   // BS*EPG
#define NTOT  38400    // BS*NE (graph nodes)
#define NMESH (BS*NN)  // 39848 mesh rows
#define NNP   5120     // NN padded to 20*256 for scan
#define EM    128      // edge-kernel tile rows
#define TROWS 256      // deg-table rows (max supported degree + 1)

// transposed decoder-weight table offsets (floats)
#define UW1T  0
#define UB1T  512
#define UW2T  1024
#define UB2T  3072
#define UW3T  3584
#define ULNGT 5632
#define ULNBT 6144
#define DWT_N 6656

typedef _Float16 f16;
typedef _Float16 f16x8 __attribute__((ext_vector_type(8)));
typedef float f32x4 __attribute__((ext_vector_type(4)));

__device__ __forceinline__ float lrelu(float x) { return x >= 0.0f ? x : 0.2f * x; }

// ---------------------------------------------------------------------------
// K0 (fused): hv0 = ln(mlp(enc_clnb_row, enc_ew1..3)) then
// m0 = ln(mlp([hv0;hv0]), elng0, elnb0).
// ---------------------------------------------------------------------------
__global__ __launch_bounds__(128)
void enc_msg0_kernel(const float* __restrict__ clnb,
                     const float* __restrict__ ew1, const float* __restrict__ eb1,
                     const float* __restrict__ ew2, const float* __restrict__ eb2,
                     const float* __restrict__ ew3,
                     const float* __restrict__ g, const float* __restrict__ b,
                     float* __restrict__ hv0,
                     const float* __restrict__ pew1, const float* __restrict__ peb1,
                     const float* __restrict__ pew2, const float* __restrict__ peb2,
                     const float* __restrict__ pew3,
                     const float* __restrict__ pg, const float* __restrict__ pb,
                     float* __restrict__ m0) {
    __shared__ float s1[HD], s2[HD], s3[HD], hv[HD];
    int j = threadIdx.x;
    // ---- encoder-constant part
    float a = eb1[j];
    for (int c = 0; c < CIN; ++c) a += clnb[c] * ew1[c * HD + j];
    s1[j] = lrelu(a);
    __syncthreads();
    a = eb2[j];
    for (int k = 0; k < HD; ++k) a += s1[k] * ew2[k * HD + j];
    s2[j] = lrelu(a);
    __syncthreads();
    a = 0.0f;
    for (int k = 0; k < HD; ++k) a += s2[k] * ew3[k * HD + j];
    s3[j] = a;
    __syncthreads();
    float m = 0.0f;
    for (int k = 0; k < HD; ++k) m += s3[k];
    m *= (1.0f / HD);
    float v = 0.0f;
    for (int k = 0; k < HD; ++k) { float d = s3[k] - m; v += d * d; }
    v *= (1.0f / HD);
    float rs = 1.0f / sqrtf(v + 1e-5f);
    float h0 = (s3[j] - m) * rs * g[j] + b[j];
    hv0[j] = h0;
    hv[j] = h0;
    __syncthreads();
    // ---- msg0 part (reads hv from LDS)
    a = peb1[j];
    for (int k = 0; k < HD; ++k) a += hv[k] * (pew1[k * HD + j] + pew1[(k + HD) * HD + j]);
    s1[j] = lrelu(a);
    __syncthreads();
    a = peb2[j];
    for (int k = 0; k < HD; ++k) a += s1[k] * pew2[k * HD + j];
    s2[j] = lrelu(a);
    __syncthreads();
    a = 0.0f;
    for (int k = 0; k < HD; ++k) a += s2[k] * pew3[k * HD + j];
    s3[j] = a;
    __syncthreads();
    m = 0.0f;
    for (int k = 0; k < HD; ++k) m += s3[k];
    m *= (1.0f / HD);
    v = 0.0f;
    for (int k = 0; k < HD; ++k) { float d = s3[k] - m; v += d * d; }
    v *= (1.0f / HD);
    rs = 1.0f / sqrtf(v + 1e-5f);
    m0[j] = (s3[j] - m) * rs * pg[j] + pb[j];
}

// ---------------------------------------------------------------------------
// Convert + transpose processor weights to f16 Wt[n][k]; block 48 = f16 copy
// of edge L1 biases; block 49 = decoder weight transpose; blocks 50..63 zero
// the edge-CSR meta region; block 64 zeros the mesh-CSR meta region + writes
// the deg-iota table index (R9: replaces the hipMemsetAsync dispatch).
// ---------------------------------------------------------------------------
__global__ __launch_bounds__(256)
void conv_all_kernel(const float* __restrict__ ew1, const float* __restrict__ ew2,
                     const float* __restrict__ ew3,
                     const float* __restrict__ nw1, const float* __restrict__ nw2,
                     const float* __restrict__ nw3, f16* __restrict__ wbuf,
                     const float* __restrict__ eb1, f16* __restrict__ eb16,
                     const float* __restrict__ uw1, const float* __restrict__ ub1,
                     const float* __restrict__ uw2, const float* __restrict__ ub2,
                     const float* __restrict__ uw3, const float* __restrict__ ulng,
                     const float* __restrict__ ulnb, float* __restrict__ dwt,
                     int* __restrict__ zeroA, int* __restrict__ zeroB,
                     int* __restrict__ degIota) {
    int b = blockIdx.x;        // 0..64
    int tid = threadIdx.x;
    if (b == 48) {
        for (int i = tid; i < DBLK * HD; i += 256)
            eb16[i] = (f16)eb1[i];
        return;
    }
    if (b == 49) {
        for (int idx = tid; idx < 512; idx += 256) {
            int o = idx >> 7, c = idx & 127;
            dwt[UW1T + idx] = uw1[c * 4 + o];
            dwt[UB1T + idx] = ub1[c * 4 + o];
            dwt[UB2T + idx] = ub2[c * 4 + o];
            dwt[ULNGT + idx] = ulng[c * 4 + o];
            dwt[ULNBT + idx] = ulnb[c * 4 + o];
        }
        for (int idx = tid; idx < 2048; idx += 256) {
            int io = idx >> 7, c = idx & 127;
            dwt[UW2T + idx] = uw2[c * 16 + io];
            dwt[UW3T + idx] = uw3[c * 16 + io];
        }
        return;
    }
    if (b >= 50 && b < 64) {    // zero deg+rowptr+cursor+bsum (461,824 B)
        uint4 z = {0, 0, 0, 0};
        for (int idx = (b - 50) * 256 + tid; idx < 28864; idx += 14 * 256)
            ((uint4*)zeroA)[idx] = z;
        return;
    }
    if (b == 64) {              // zero mdeg+mrow+mcur+mbsum (62,464 B) + iota
        uint4 z = {0, 0, 0, 0};
        for (int idx = tid; idx < 3904; idx += 256)
            ((uint4*)zeroB)[idx] = z;
        degIota[tid] = tid;     // 256 threads, TROWS=256
        return;
    }
    int d = b >> 3, m = b & 7;
    const float* src;
    switch (m) {
        case 0: src = ew1 + (size_t)d * 2 * HD * HD; break;
        case 1: src = ew1 + (size_t)d * 2 * HD * HD + HD * HD; break;
        case 2: src = ew2 + (size_t)d * HD * HD; break;
        case 3: src = ew3 + (size_t)d * HD * HD; break;
        case 4: src = nw1 + (size_t)d * 2 * HD * HD; break;
        case 5: src = nw1 + (size_t)d * 2 * HD * HD + HD * HD; break;
        case 6: src = nw2 + (size_t)d * HD * HD; break;
        default: src = nw3 + (size_t)d * HD * HD; break;
    }
    f16* out = wbuf + (size_t)b * HD * HD;
    for (int idx = tid; idx < HD * HD; idx += 256) {
        int n = idx >> 7, k = idx & 127;
        out[idx] = (f16)src[k * HD + n];   // Wt[n][k] = W[k][n]
    }
}

// ---------------------------------------------------------------------------
// Fused CSR build (counting sort), edge graph (by dest) + mesh (by conn) in
// single grids. Mesh arrays in a DEDICATED region (R5 lesson).
// ---------------------------------------------------------------------------
#define EHB (NEDGE / 256)     // 600 edge hist blocks
#define MHB (NE * 4 / 256)    // 75 mesh hist blocks
#define ESB (NTOT / 256)      // 150 edge scan blocks
#define MSB (NNP / 256)       // 20 mesh scan blocks

__global__ __launch_bounds__(256)
void prep_hist(const int* __restrict__ e_dst, const int* __restrict__ conn,
               int* __restrict__ deg, int* __restrict__ mdeg) {
    int b = blockIdx.x;
    if (b < EHB) {
        int e = b * 256 + threadIdx.x;
        atomicAdd(&deg[e_dst[e]], 1);
    } else {
        int idx = (b - EHB) * 256 + threadIdx.x;   // < 19200 exact
        atomicAdd(&mdeg[conn[idx]], 1);
    }
}

__device__ __forceinline__ void scan1_body(const int* __restrict__ deg,
                                           int* __restrict__ rowptr,
                                           int* __restrict__ bsum, int bi) {
    __shared__ int s[256];
    int i = bi * 256 + threadIdx.x;
    int v = deg[i];
    s[threadIdx.x] = v;
    __syncthreads();
    for (int off = 1; off < 256; off <<= 1) {
        int t = (threadIdx.x >= off) ? s[threadIdx.x - off] : 0;
        __syncthreads();
        s[threadIdx.x] += t;
        __syncthreads();
    }
    rowptr[i] = s[threadIdx.x] - v;          // exclusive
    if (threadIdx.x == 255) bsum[bi] = s[255];
}

__global__ __launch_bounds__(256)
void prep_scan1(const int* __restrict__ deg, int* __restrict__ rowptr,
                int* __restrict__ bsum,
                const int* __restrict__ mdeg, int* __restrict__ mrow,
                int* __restrict__ mbsum) {
    int b = blockIdx.x;
    if (b < ESB) scan1_body(deg, rowptr, bsum, b);
    else         scan1_body(mdeg, mrow, mbsum, b - ESB);
}

__device__ __forceinline__ void scan2_body(int* __restrict__ bsum, int nb) {
    __shared__ int s[256];
    int v = (threadIdx.x < nb) ? bsum[threadIdx.x] : 0;
    s[threadIdx.x] = v;
    __syncthreads();
    for (int off = 1; off < 256; off <<= 1) {
        int t = (threadIdx.x >= off) ? s[threadIdx.x - off] : 0;
        __syncthreads();
        s[threadIdx.x] += t;
        __syncthreads();
    }
    if (threadIdx.x < nb) bsum[threadIdx.x] = s[threadIdx.x] - v;   // exclusive
}

__global__ __launch_bounds__(256)
void prep_scan2(int* __restrict__ bsum, int* __restrict__ mbsum) {
    if (blockIdx.x == 0) scan2_body(bsum, ESB);
    else                 scan2_body(mbsum, MSB);
}

__global__ __launch_bounds__(256)
void prep_scan3(int* __restrict__ rowptr, const int* __restrict__ bsum,
                int* __restrict__ mrow, const int* __restrict__ mbsum) {
    int b = blockIdx.x;
    if (b < ESB) {
        int i = b * 256 + threadIdx.x;
        rowptr[i] += bsum[b];
    } else {
        int i = (b - ESB) * 256 + threadIdx.x;
        mrow[i] += mbsum[b - ESB];
    }
}

// R9: edge branch additionally emits per-edge DEST/SRC degrees so the d=1
// edge kernel can gather from the 256-row deg tables with zero code change.
__global__ __launch_bounds__(256)
void prep_scatter(const int* __restrict__ dest, const int* __restrict__ srcv,
                  const int* __restrict__ rowptr, int* __restrict__ cursor,
                  int* __restrict__ dsorted, int* __restrict__ ssorted,
                  const int* __restrict__ conn, const int* __restrict__ mrow,
                  int* __restrict__ mcur, int* __restrict__ mslot,
                  const int* __restrict__ deg,
                  int* __restrict__ ddegs, int* __restrict__ sdegs) {
    int b = blockIdx.x;
    if (b < EHB) {
        int e = b * 256 + threadIdx.x;
        int d = dest[e];
        int s = srcv[e];
        int pos = rowptr[d] + atomicAdd(&cursor[d], 1);
        dsorted[pos] = d;
        ssorted[pos] = s;
        ddegs[pos] = deg[d];
        sdegs[pos] = deg[s];
    } else {
        int idx = (b - EHB) * 256 + threadIdx.x;   // < 19200 exact
        int nd = conn[idx];
        int pos = mrow[nd] + atomicAdd(&mcur[nd], 1);
        mslot[pos] = idx;
    }
}

// ---------------------------------------------------------------------------
// Shared GEMM helpers (R0 structure — all skeleton edits measured neutral-to-
// negative in rounds 1-4).
// ---------------------------------------------------------------------------
template <int NT>
__device__ __forceinline__ void stage_w(const f16* __restrict__ Wg, f16 (*Bt)[HD + 8],
                                        int tid) {
    #pragma unroll
    for (int t = 0; t < 2048 / NT; ++t) {
        int idx = tid + t * NT;             // 16B chunks of 128x128 f16
        int r = idx >> 4, c = (idx & 15) * 8;
        *(uint4*)(&Bt[r][c]) = *(const uint4*)(Wg + (size_t)r * HD + c);
    }
}

__device__ __forceinline__ void mfma_pass(const f16 (*A)[HD + 8], const f16 (*Bt)[HD + 8],
                                          int rt_base, int ct_base, int ln, int quad,
                                          f32x4 acc[2][4]) {
    #pragma unroll
    for (int ks = 0; ks < 4; ++ks) {
        int kb = ks * 32 + quad * 8;
        f16x8 a0 = *(const f16x8*)(&A[rt_base + ln][kb]);
        f16x8 a1 = *(const f16x8*)(&A[rt_base + 16 + ln][kb]);
        #pragma unroll
        for (int c = 0; c < 4; ++c) {
            f16x8 b = *(const f16x8*)(&Bt[ct_base + c * 16 + ln][kb]);
            acc[0][c] = __builtin_amdgcn_mfma_f32_16x16x32_f16(a0, b, acc[0][c], 0, 0, 0);
            acc[1][c] = __builtin_amdgcn_mfma_f32_16x16x32_f16(a1, b, acc[1][c], 0, 0, 0);
        }
    }
}

// ---------------------------------------------------------------------------
// Edge kernel (d>=1), dest-sorted, M=128 tile, 512 threads (8 waves).
// Direct per-thread global index loads (R7). For d=1 the caller passes the
// deg TABLES as P1/P2 and per-edge degrees as the index arrays (R9) — the
// kernel itself is unchanged.
// ---------------------------------------------------------------------------
__global__ __launch_bounds__(512, 4)
void gn_edge(const f16* __restrict__ P1, const f16* __restrict__ P2,
             const int* __restrict__ dsorted, const int* __restrict__ ssorted,
             const f16* __restrict__ W2, const f16* __restrict__ W3,
             const f16* __restrict__ b1h, const float* __restrict__ b2,
             const float* __restrict__ g, const float* __restrict__ bln,
             f16* __restrict__ msg) {
    __shared__ __align__(16) f16 As[EM][HD + 8];
    __shared__ __align__(16) f16 Bt[HD][HD + 8];
    __shared__ float red[EM][2][2];

    const int tid = threadIdx.x;
    const int base = blockIdx.x * EM;
    const int wave = tid >> 6, lane = tid & 63;
    const int ln = lane & 15, quad = lane >> 4;
    const int rt_base = (wave >> 1) * 32;     // 0,32,64,96
    const int ct_base = (wave & 1) * 64;
    const int half = wave & 1;
    const int r0 = tid >> 4;                  // gather row (+32*it)
    const int cg = (tid & 15) * 8;            // gather col

    const f16 k02s = (f16)0.2f;
    const f16x8 k02 = {k02s, k02s, k02s, k02s, k02s, k02s, k02s, k02s};

    // direct per-thread index loads (no LDS, no barrier)
    int dI[4], sI[4];
    #pragma unroll
    for (int it = 0; it < 4; ++it) {
        dI[it] = dsorted[base + r0 + it * 32];
        sI[it] = ssorted[base + r0 + it * 32];
    }
    stage_w<512>(W2, Bt, tid);
    const f16x8 bb = *(const f16x8*)(b1h + cg);
    #pragma unroll
    for (int it = 0; it < 4; ++it) {
        f16x8 p1 = *(const f16x8*)(P1 + (size_t)dI[it] * HD + cg);
        f16x8 p2 = *(const f16x8*)(P2 + (size_t)sI[it] * HD + cg);
        f16x8 s = p1 + p2 + bb;             // v_pk_add_f16
        *(f16x8*)(&As[r0 + it * 32][cg]) = __builtin_elementwise_max(s, s * k02);
    }
    __syncthreads();

    f32x4 acc[2][4];

    // ---- Layer 2
    #pragma unroll
    for (int c = 0; c < 4; ++c) {
        float bj = b2[ct_base + c * 16 + ln];
        f32x4 bv = {bj, bj, bj, bj};
        acc[0][c] = bv; acc[1][c] = bv;
    }
    mfma_pass(As, Bt, rt_base, ct_base, ln, quad, acc);
    __syncthreads();
    stage_w<512>(W3, Bt, tid);
    #pragma unroll
    for (int i = 0; i < 2; ++i)
        #pragma unroll
        for (int c = 0; c < 4; ++c)
            #pragma unroll
            for (int r = 0; r < 4; ++r)
                As[rt_base + i * 16 + quad * 4 + r][ct_base + c * 16 + ln] =
                    (f16)lrelu(acc[i][c][r]);
    __syncthreads();

    // ---- Layer 3
    #pragma unroll
    for (int c = 0; c < 4; ++c) { f32x4 z = {0,0,0,0}; acc[0][c] = z; acc[1][c] = z; }
    mfma_pass(As, Bt, rt_base, ct_base, ln, quad, acc);

    // ---- LayerNorm stats
    #pragma unroll
    for (int i = 0; i < 2; ++i)
        #pragma unroll
        for (int r = 0; r < 4; ++r) {
            float s = acc[i][0][r] + acc[i][1][r] + acc[i][2][r] + acc[i][3][r];
            float q = acc[i][0][r] * acc[i][0][r] + acc[i][1][r] * acc[i][1][r] +
                      acc[i][2][r] * acc[i][2][r] + acc[i][3][r] * acc[i][3][r];
            s += __shfl_xor(s, 1); q += __shfl_xor(q, 1);
            s += __shfl_xor(s, 2); q += __shfl_xor(q, 2);
            s += __shfl_xor(s, 4); q += __shfl_xor(q, 4);
            s += __shfl_xor(s, 8); q += __shfl_xor(q, 8);
            if (ln == 0) {
                int row = rt_base + i * 16 + quad * 4 + r;
                red[row][half][0] = s;
                red[row][half][1] = q;
            }
        }
    __syncthreads();

    // ---- Epilogue: LN scale + plain f16 store to msg (sorted slot order)
    float gv[4], bv[4];
    #pragma unroll
    for (int c = 0; c < 4; ++c) {
        int col = ct_base + c * 16 + ln;
        gv[c] = g[col]; bv[c] = bln[col];
    }
    #pragma unroll
    for (int i = 0; i < 2; ++i)
        #pragma unroll
        for (int r = 0; r < 4; ++r) {
            int row = rt_base + i * 16 + quad * 4 + r;
            float s = red[row][0][0] + red[row][1][0];
            float q = red[row][0][1] + red[row][1][1];
            float m = s * (1.0f / HD);
            float var = q * (1.0f / HD) - m * m;
            float rs = 1.0f / sqrtf(var + 1e-5f);
            #pragma unroll
            for (int c = 0; c < 4; ++c) {
                int col = ct_base + c * 16 + ln;
                float v = (acc[i][c][r] - m) * rs * gv[c] + bv[c];
                msg[(size_t)(base + row) * HD + col] = (f16)v;
            }
        }
}

// ---------------------------------------------------------------------------
// Node kernel — R0 structure (64-row As, 256 threads, 3 blocks/CU) with:
//  * aggr msg-sum unrolled by 4 (R6); direct rowptr/deg loads (R7);
//  * AGGR==0 hreg from hv0 (R7) — also serves as the deg-TABLE builder (R9):
//    launched with 4 blocks + iota deg array, it produces tabH/tabP1/tabP2
//    rows bit-identical to the old 600-block node0 output;
//  * HTAB (R9): node d=1 reads hreg via tabH[deg[n]] instead of h16;
//  * T14 (R9, isolated): nW1a loads issued before LN stats, nW1b loads under
//    the nW1a GEMM + P1 stores; Bt ds-writes at the existing barriers
//    (same barrier count, two serial stage latencies removed);
//  * DECF (R8): fused decoder stage 1; R9: dwt staged into the free Bt LDS
//    (26.6KB <= 34.8KB) after the stats barrier — removes 208 scattered L2
//    loads per thread.
// ---------------------------------------------------------------------------
template <int AGGR, bool PROD, bool DECF, bool HTAB>
__global__ __launch_bounds__(256, 3)
void gn_node(f16* __restrict__ h16, const f16* __restrict__ msg,
             const int* __restrict__ rowptr, const int* __restrict__ deg,
             const float* __restrict__ m0, const float* __restrict__ hv0,
             const f16* __restrict__ htab,
             const f16* __restrict__ W1a, const f16* __restrict__ W1b,
             const f16* __restrict__ W2, const f16* __restrict__ W3,
             const float* __restrict__ b1, const float* __restrict__ b2,
             const float* __restrict__ g, const float* __restrict__ bln,
             const f16* __restrict__ nW1a, const f16* __restrict__ nW1b,
             f16* __restrict__ P1, f16* __restrict__ P2,
             const float* __restrict__ dwt, f16* __restrict__ uval) {
    __shared__ __align__(16) f16 As[64][HD + 8];
    __shared__ __align__(16) f16 Bt[HD][HD + 8];
    __shared__ float red[64][2][2];

    const int tid = threadIdx.x;
    const int base = blockIdx.x * 64;
    const int wave = tid >> 6, lane = tid & 63;
    const int ln = lane & 15, quad = lane >> 4;
    const int rt_base = (wave >> 1) * 32;
    const int ct_base = (wave & 1) * 64;
    const int half = wave & 1;

    // ---- Stage: aggr -> As, h -> hreg (VGPRs). Direct index loads (no LDS).
    f16x8 hreg[4];
    #pragma unroll
    for (int t = 0; t < 4; ++t) {
        int r = (tid >> 4) + t * 16;        // 0..63
        int c = (tid & 15) * 8;
        if (AGGR == 0) {
            f16x8 hz;
            #pragma unroll
            for (int u = 0; u < 8; ++u) hz[u] = (f16)hv0[c + u];
            hreg[t] = hz;
            float sc = (float)deg[base + r];
            f16x8 o;
            #pragma unroll
            for (int u = 0; u < 8; ++u) o[u] = (f16)(sc * m0[c + u]);
            *(f16x8*)(&As[r][c]) = o;
        } else {
            if (HTAB)
                hreg[t] = *(const f16x8*)(htab + (size_t)deg[base + r] * HD + c);
            else
                hreg[t] = *(const f16x8*)(h16 + (size_t)(base + r) * HD + c);
            int rp = rowptr[base + r], dg = deg[base + r];
            float a[8] = {0, 0, 0, 0, 0, 0, 0, 0};
            int j = 0;
            for (; j + 4 <= dg; j += 4) {   // 4 independent loads in flight
                f16x8 v0 = *(const f16x8*)(msg + (size_t)(rp + j) * HD + c);
                f16x8 v1 = *(const f16x8*)(msg + (size_t)(rp + j + 1) * HD + c);
                f16x8 v2 = *(const f16x8*)(msg + (size_t)(rp + j + 2) * HD + c);
                f16x8 v3 = *(const f16x8*)(msg + (size_t)(rp + j + 3) * HD + c);
                #pragma unroll
                for (int u = 0; u < 8; ++u)
                    a[u] += ((float)v0[u] + (float)v1[u]) + ((float)v2[u] + (float)v3[u]);
            }
            for (; j < dg; ++j) {
                f16x8 mv = *(const f16x8*)(msg + (size_t)(rp + j) * HD + c);
                #pragma unroll
                for (int u = 0; u < 8; ++u) a[u] += (float)mv[u];
            }
            f16x8 o;
            #pragma unroll
            for (int u = 0; u < 8; ++u) o[u] = (f16)a[u];
            *(f16x8*)(&As[r][c]) = o;
        }
    }
    stage_w<256>(W1b, Bt, tid);
    __syncthreads();

    f32x4 acc[2][4];
    #pragma unroll
    for (int c = 0; c < 4; ++c) {
        float bj = b1[ct_base + c * 16 + ln];
        f32x4 bb = {bj, bj, bj, bj};
        acc[0][c] = bb; acc[1][c] = bb;
    }
    mfma_pass(As, Bt, rt_base, ct_base, ln, quad, acc);   // aggr @ W1b
    __syncthreads();

    #pragma unroll
    for (int t = 0; t < 4; ++t) {
        int r = (tid >> 4) + t * 16;
        int c = (tid & 15) * 8;
        *(f16x8*)(&As[r][c]) = hreg[t];
    }
    stage_w<256>(W1a, Bt, tid);
    __syncthreads();
    mfma_pass(As, Bt, rt_base, ct_base, ln, quad, acc);   // + h @ W1a
    __syncthreads();

    stage_w<256>(W2, Bt, tid);
    #pragma unroll
    for (int i = 0; i < 2; ++i)
        #pragma unroll
        for (int c = 0; c < 4; ++c)
            #pragma unroll
            for (int r = 0; r < 4; ++r)
                As[rt_base + i * 16 + quad * 4 + r][ct_base + c * 16 + ln] =
                    (f16)lrelu(acc[i][c][r]);
    __syncthreads();

    #pragma unroll
    for (int c = 0; c < 4; ++c) {
        float bj = b2[ct_base + c * 16 + ln];
        f32x4 bb = {bj, bj, bj, bj};
        acc[0][c] = bb; acc[1][c] = bb;
    }
    mfma_pass(As, Bt, rt_base, ct_base, ln, quad, acc);   // act1 @ W2
    __syncthreads();
    stage_w<256>(W3, Bt, tid);
    #pragma unroll
    for (int i = 0; i < 2; ++i)
        #pragma unroll
        for (int c = 0; c < 4; ++c)
            #pragma unroll
            for (int r = 0; r < 4; ++r)
                As[rt_base + i * 16 + quad * 4 + r][ct_base + c * 16 + ln] =
                    (f16)lrelu(acc[i][c][r]);
    __syncthreads();

    #pragma unroll
    for (int c = 0; c < 4; ++c) { f32x4 z = {0,0,0,0}; acc[0][c] = z; acc[1][c] = z; }
    mfma_pass(As, Bt, rt_base, ct_base, ln, quad, acc);   // act2 @ W3

    // T14: issue nW1a loads now; latency hides under LN stats + epilogue.
    uint4 wr[8];
    if (PROD) {
        #pragma unroll
        for (int t = 0; t < 8; ++t) {
            int idx = tid + t * 256;
            int r = idx >> 4, c = (idx & 15) * 8;
            wr[t] = *(const uint4*)(nW1a + (size_t)r * HD + c);
        }
    }

    // ---- LayerNorm stats
    #pragma unroll
    for (int i = 0; i < 2; ++i)
        #pragma unroll
        for (int r = 0; r < 4; ++r) {
            float s = acc[i][0][r] + acc[i][1][r] + acc[i][2][r] + acc[i][3][r];
            float q = acc[i][0][r] * acc[i][0][r] + acc[i][1][r] * acc[i][1][r] +
                      acc[i][2][r] * acc[i][2][r] + acc[i][3][r] * acc[i][3][r];
            s += __shfl_xor(s, 1); q += __shfl_xor(q, 1);
            s += __shfl_xor(s, 2); q += __shfl_xor(q, 2);
            s += __shfl_xor(s, 4); q += __shfl_xor(q, 4);
            s += __shfl_xor(s, 8); q += __shfl_xor(q, 8);
            if (ln == 0) {
                int row = rt_base + i * 16 + quad * 4 + r;
                red[row][half][0] = s;
                red[row][half][1] = q;
            }
        }
    __syncthreads();    // red visible; all Bt(W3) reads complete

    float gv[4], bv[4];
    #pragma unroll
    for (int c = 0; c < 4; ++c) {
        int col = ct_base + c * 16 + ln;
        gv[c] = g[col]; bv[c] = bln[col];
    }

    if (!DECF) {
        #pragma unroll
        for (int i = 0; i < 2; ++i)
            #pragma unroll
            for (int r = 0; r < 4; ++r) {
                int row = rt_base + i * 16 + quad * 4 + r;
                float s = red[row][0][0] + red[row][1][0];
                float q = red[row][0][1] + red[row][1][1];
                float m = s * (1.0f / HD);
                float var = q * (1.0f / HD) - m * m;
                float rs = 1.0f / sqrtf(var + 1e-5f);
                #pragma unroll
                for (int c = 0; c < 4; ++c) {
                    int col = ct_base + c * 16 + ln;
                    float v = (acc[i][c][r] - m) * rs * gv[c] + bv[c];
                    f16 hv = (f16)v;
                    h16[(size_t)(base + row) * HD + col] = hv;
                    if (PROD) As[row][col] = hv;    // h_new for P production
                }
            }
    } else {
        // ---- Fused decoder stage 1: dwt staged to LDS (Bt free after the
        // stats barrier), then per-element upsample MLP + LN(4) -> uval.
        float* dls = (float*)&Bt[0][0];
        for (int idx = tid; idx < DWT_N / 4; idx += 256)
            ((float4*)dls)[idx] = ((const float4*)dwt)[idx];
        __syncthreads();

        float mm[2][4], rr[2][4];
        #pragma unroll
        for (int i = 0; i < 2; ++i)
            #pragma unroll
            for (int r = 0; r < 4; ++r) {
                int row = rt_base + i * 16 + quad * 4 + r;
                float s = red[row][0][0] + red[row][1][0];
                float q = red[row][0][1] + red[row][1][1];
                float m = s * (1.0f / HD);
                float var = q * (1.0f / HD) - m * m;
                mm[i][r] = m;
                rr[i][r] = 1.0f / sqrtf(var + 1e-5f);
            }
        #pragma unroll
        for (int c = 0; c < 4; ++c) {
            int col = ct_base + c * 16 + ln;
            float w1v[4], wb1[4], wb2[4], lg4[4], lb4[4];
            #pragma unroll
            for (int o = 0; o < 4; ++o) {
                w1v[o] = dls[UW1T + o * 128 + col];
                wb1[o] = dls[UB1T + o * 128 + col];
                wb2[o] = dls[UB2T + o * 128 + col];
                lg4[o] = dls[ULNGT + o * 128 + col];
                lb4[o] = dls[ULNBT + o * 128 + col];
            }
            float w2v[16], w3v[16];
            #pragma unroll
            for (int io = 0; io < 16; ++io) {
                w2v[io] = dls[UW2T + io * 128 + col];
                w3v[io] = dls[UW3T + io * 128 + col];
            }
            #pragma unroll
            for (int i = 0; i < 2; ++i)
                #pragma unroll
                for (int r = 0; r < 4; ++r) {
                    int row = rt_base + i * 16 + quad * 4 + r;
                    float v = (acc[i][c][r] - mm[i][r]) * rr[i][r] * gv[c] + bv[c];
                    float s = (float)(f16)v;     // match h16 rounding
                    float u1[4], u2[4], u3[4];
                    #pragma unroll
                    for (int o = 0; o < 4; ++o)
                        u1[o] = lrelu(s * w1v[o] + wb1[o]);
                    #pragma unroll
                    for (int o = 0; o < 4; ++o) {
                        float a = wb2[o];
                        #pragma unroll
                        for (int i2 = 0; i2 < 4; ++i2) a += u1[i2] * w2v[i2 * 4 + o];
                        u2[o] = lrelu(a);
                    }
                    #pragma unroll
                    for (int o = 0; o < 4; ++o) {
                        float a = 0.f;
                        #pragma unroll
                        for (int i2 = 0; i2 < 4; ++i2) a += u2[i2] * w3v[i2 * 4 + o];
                        u3[o] = a;
                    }
                    float m4 = 0.25f * (u3[0] + u3[1] + u3[2] + u3[3]);
                    float var4 = 0.f;
                    #pragma unroll
                    for (int o = 0; o < 4; ++o) { float d = u3[o] - m4; var4 += d * d; }
                    var4 *= 0.25f;
                    float rs4 = 1.0f / sqrtf(var4 + 1e-5f);
                    size_t ub = (size_t)(base + row) * 4 * HD + col;
                    #pragma unroll
                    for (int o = 0; o < 4; ++o)
                        uval[ub + (size_t)o * HD] =
                            (f16)((u3[o] - m4) * rs4 * lg4[o] + lb4[o]);
                }
        }
    }

    if (PROD) {
        __syncthreads();                 // h_new in As visible; Bt free
        #pragma unroll
        for (int t = 0; t < 8; ++t) {    // Bt <- nW1a (from regs)
            int idx = tid + t * 256;
            int r = idx >> 4, c = (idx & 15) * 8;
            *(uint4*)(&Bt[r][c]) = wr[t];
        }
        #pragma unroll
        for (int t = 0; t < 8; ++t) {    // T14: issue nW1b loads now
            int idx = tid + t * 256;
            int r = idx >> 4, c = (idx & 15) * 8;
            wr[t] = *(const uint4*)(nW1b + (size_t)r * HD + c);
        }
        __syncthreads();                 // Bt(nW1a) visible
        #pragma unroll
        for (int c = 0; c < 4; ++c) { f32x4 z = {0,0,0,0}; acc[0][c] = z; acc[1][c] = z; }
        mfma_pass(As, Bt, rt_base, ct_base, ln, quad, acc);
        #pragma unroll
        for (int i = 0; i < 2; ++i)
            #pragma unroll
            for (int c = 0; c < 4; ++c)
                #pragma unroll
                for (int r = 0; r < 4; ++r)
                    P1[(size_t)(base + rt_base + i * 16 + quad * 4 + r) * HD +
                       ct_base + c * 16 + ln] = (f16)acc[i][c][r];
        __syncthreads();                 // all Bt(nW1a) reads done
        #pragma unroll
        for (int t = 0; t < 8; ++t) {    // Bt <- nW1b
            int idx = tid + t * 256;
            int r = idx >> 4, c = (idx & 15) * 8;
            *(uint4*)(&Bt[r][c]) = wr[t];
        }
        __syncthreads();                 // Bt(nW1b) visible
        #pragma unroll
        for (int c = 0; c < 4; ++c) { f32x4 z = {0,0,0,0}; acc[0][c] = z; acc[1][c] = z; }
        mfma_pass(As, Bt, rt_base, ct_base, ln, quad, acc);
        #pragma unroll
        for (int i = 0; i < 2; ++i)
            #pragma unroll
            for (int c = 0; c < 4; ++c)
                #pragma unroll
                for (int r = 0; r < 4; ++r)
                    P2[(size_t)(base + rt_base + i * 16 + quad * 4 + r) * HD +
                       ct_base + c * 16 + ln] = (f16)acc[i][c][r];
    }
}

// ---------------------------------------------------------------------------
// Decoder stage 2 (fused gather + output MLP): one wave per mesh row.
// Degree loop unrolled by 4 (R8).
// ---------------------------------------------------------------------------
__global__ __launch_bounds__(256)
void dec_gather_out(const f16* __restrict__ uval,
                    const int* __restrict__ mrow, const int* __restrict__ mdeg,
                    const int* __restrict__ mslot,
                    const float* __restrict__ cw1, const float* __restrict__ cb1,
                    const float* __restrict__ cw2, const float* __restrict__ cb2,
                    const float* __restrict__ cw3,
                    float* __restrict__ o, int nrows) {
    int r = blockIdx.x * 4 + (threadIdx.x >> 6);
    if (r >= nrows) return;
    int lane = threadIdx.x & 63;
    int b = r / NN, n = r - b * NN;
    int rp = mrow[n], dg = mdeg[n];
    size_t boff = (size_t)b * NE * 4;
    float a0 = 0.f, a1 = 0.f;
    int j = 0;
    for (; j + 4 <= dg; j += 4) {
        int s0 = mslot[rp + j], s1 = mslot[rp + j + 1];
        int s2 = mslot[rp + j + 2], s3 = mslot[rp + j + 3];
        const f16* u0 = uval + (boff + s0) * HD + lane * 2;
        const f16* u1 = uval + (boff + s1) * HD + lane * 2;
        const f16* u2 = uval + (boff + s2) * HD + lane * 2;
        const f16* u3 = uval + (boff + s3) * HD + lane * 2;
        float b00 = (float)u0[0], b01 = (float)u0[1];
        float b10 = (float)u1[0], b11 = (float)u1[1];
        float b20 = (float)u2[0], b21 = (float)u2[1];
        float b30 = (float)u3[0], b31 = (float)u3[1];
        a0 += (b00 + b10) + (b20 + b30);
        a1 += (b01 + b11) + (b21 + b31);
    }
    for (; j < dg; ++j) {
        int slot = mslot[rp + j];
        const f16* up = uval + (boff + slot) * HD + lane * 2;
        a0 += (float)up[0];
        a1 += (float)up[1];
    }
    int c0 = lane * 2, c1 = lane * 2 + 1;
    float s[3];
    #pragma unroll
    for (int k = 0; k < 3; ++k)
        s[k] = a0 * cw1[c0 * 3 + k] + a1 * cw1[c1 * 3 + k];
    #pragma unroll
    for (int off = 32; off >= 1; off >>= 1) {
        s[0] += __shfl_down(s[0], off);
        s[1] += __shfl_down(s[1], off);
        s[2] += __shfl_down(s[2], off);
    }
    if (lane == 0) {
        float t1[3], t2[3];
        #pragma unroll
        for (int k = 0; k < 3; ++k) t1[k] = lrelu(s[k] + cb1[k]);
        #pragma unroll
        for (int k = 0; k < 3; ++k) {
            float a = cb2[k];
            #pragma unroll
            for (int q = 0; q < 3; ++q) a += t1[q] * cw2[q * 3 + k];
            t2[k] = lrelu(a);
        }
        #pragma unroll
        for (int k = 0; k < 3; ++k) {
            float a = 0.f;
            #pragma unroll
            for (int q = 0; q < 3; ++q) a += t2[q] * cw3[q * 3 + k];
            o[(size_t)r * 3 + k] = a;
        }
    }
}

// ---------------------------------------------------------------------------
extern "C" void kernel_launch(void* const* d_in, const int* in_sizes, int n_in,
                              void* d_out, int out_size, void* d_ws, size_t ws_size,
                              hipStream_t stream) {
    const int* elem_conn = (const int*)d_in[1];
    const int* edge_index = (const int*)d_in[2];
    const int* e_src = edge_index;          // row 0
    const int* e_dst = edge_index + NEDGE;  // row 1
    const float* enc_clnb = (const float*)d_in[9];
    const float* enc_ew1 = (const float*)d_in[10];
    const float* enc_eb1 = (const float*)d_in[11];
    const float* enc_ew2 = (const float*)d_in[12];
    const float* enc_eb2 = (const float*)d_in[13];
    const float* enc_ew3 = (const float*)d_in[14];
    const float* enc_elng = (const float*)d_in[15];
    const float* enc_elnb = (const float*)d_in[16];
    const float* p_ew1 = (const float*)d_in[17];
    const float* p_eb1 = (const float*)d_in[18];
    const float* p_ew2 = (const float*)d_in[19];
    const float* p_eb2 = (const float*)d_in[20];
    const float* p_ew3 = (const float*)d_in[21];
    const float* p_elng = (const float*)d_in[22];
    const float* p_elnb = (const float*)d_in[23];
    const float* p_nw1 = (const float*)d_in[24];
    const float* p_nb1 = (const float*)d_in[25];
    const float* p_nw2 = (const float*)d_in[26];
    const float* p_nb2 = (const float*)d_in[27];
    const float* p_nw3 = (const float*)d_in[28];
    const float* p_nlng = (const float*)d_in[29];
    const float* p_nlnb = (const float*)d_in[30];
    const float* dec_uw1 = (const float*)d_in[31];
    const float* dec_ub1 = (const float*)d_in[32];
    const float* dec_uw2 = (const float*)d_in[33];
    const float* dec_ub2 = (const float*)d_in[34];
    const float* dec_uw3 = (const float*)d_in[35];
    const float* dec_ulng = (const float*)d_in[36];
    const float* dec_ulnb = (const float*)d_in[37];
    const float* dec_cw1 = (const float*)d_in[38];
    const float* dec_cb1 = (const float*)d_in[39];
    const float* dec_cw2 = (const float*)d_in[40];
    const float* dec_cb2 = (const float*)d_in[41];
    const float* dec_cw3 = (const float*)d_in[42];

    // Workspace layout (bytes), ~113 MB of the 256 MiB workspace.
    char* ws = (char*)d_ws;
    f16*   h16     = (f16*)(ws);                        //  9,830,400
    f16*   wbuf    = (f16*)(ws + 9830400);              //  1,572,864
    float* hv0     = (float*)(ws + 11403264);           //  512
    float* m0      = (float*)(ws + 11403776);           //  512
    f16*   P1      = (f16*)(ws + 11404288);             //  9,830,400
    f16*   P2      = (f16*)(ws + 21234688);             //  9,830,400
    f16*   msg     = (f16*)(ws + 31065088);             // 39,321,600
    int*   deg     = (int*)(ws + 70386688);             //  153,600
    int*   rowptr  = (int*)(ws + 70540288);             //  153,600
    int*   cursor  = (int*)(ws + 70693888);             //  153,600
    int*   bsum    = (int*)(ws + 70847488);             //  1,024
    int*   dsorted = (int*)(ws + 70848512);             //  614,400
    int*   ssorted = (int*)(ws + 71462912);             //  614,400
    f16*   eb16    = (f16*)(ws + 72077312);             //  1,536
    int*   mdeg    = (int*)(ws + 72078848);             //  20,480 (NNP)
    int*   mrow    = (int*)(ws + 72099328);             //  20,480
    int*   mcur    = (int*)(ws + 72119808);             //  20,480
    int*   mbsum   = (int*)(ws + 72140288);             //  1,024
    int*   mslot   = (int*)(ws + 72141312);             //  76,800
    float* dwt     = (float*)(ws + 72218112);           //  26,624
    f16*   uval    = (f16*)(ws + 72244736);             // 39,321,600
    int*   ddegs   = (int*)(ws + 111566336);            //  614,400
    int*   sdegs   = (int*)(ws + 112180736);            //  614,400
    f16*   tabH    = (f16*)(ws + 112795136);            //  65,536 (256x128)
    f16*   tabP1   = (f16*)(ws + 112860672);            //  65,536
    f16*   tabP2   = (f16*)(ws + 112926208);            //  65,536
    int*   degIota = (int*)(ws + 112991744);            //  1,024

    // ---- Prologue (3 dispatches, memset folded into conv_all)
    enc_msg0_kernel<<<1, 128, 0, stream>>>(
        enc_clnb, enc_ew1, enc_eb1, enc_ew2, enc_eb2, enc_ew3, enc_elng, enc_elnb, hv0,
        p_ew1, p_eb1, p_ew2, p_eb2, p_ew3, p_elng, p_elnb, m0);
    conv_all_kernel<<<65, 256, 0, stream>>>(p_ew1, p_ew2, p_ew3,
                                            p_nw1, p_nw2, p_nw3, wbuf, p_eb1, eb16,
                                            dec_uw1, dec_ub1, dec_uw2, dec_ub2,
                                            dec_uw3, dec_ulng, dec_ulnb, dwt,
                                            deg, mdeg, degIota);

    // ---- d=0 as a 256-row deg table (R9): same kernel, 4 blocks, iota degs.
    // Produces tabH/tabP1/tabP2 rows bit-identical to the old 600-block node0.
    {
        const f16* wd = wbuf;                       // d=0
        const f16* wn = wbuf + (size_t)8 * HD * HD; // d=1
        gn_node<0, true, false, false><<<TROWS / 64, 256, 0, stream>>>(
            tabH, nullptr, nullptr, degIota, m0, hv0, nullptr,
            wd + 4 * HD * HD, wd + 5 * HD * HD, wd + 6 * HD * HD, wd + 7 * HD * HD,
            p_nb1, p_nb2, p_nlng, p_nlnb,
            wn + 0 * HD * HD, wn + 1 * HD * HD, tabP1, tabP2, nullptr, nullptr);
    }

    // ---- Fused CSR builds: 5 dispatches (scatter also emits ddegs/sdegs).
    prep_hist<<<EHB + MHB, 256, 0, stream>>>(e_dst, elem_conn, deg, mdeg);
    prep_scan1<<<ESB + MSB, 256, 0, stream>>>(deg, rowptr, bsum, mdeg, mrow, mbsum);
    prep_scan2<<<2, 256, 0, stream>>>(bsum, mbsum);
    prep_scan3<<<ESB + MSB, 256, 0, stream>>>(rowptr, bsum, mrow, mbsum);
    prep_scatter<<<EHB + MHB, 256, 0, stream>>>(e_dst, e_src, rowptr, cursor,
                                                dsorted, ssorted,
                                                elem_conn, mrow, mcur, mslot,
                                                deg, ddegs, sdegs);

    // ---- d=1..5. Edge d=1 gathers from the deg tables (indices = degrees);
    // node d=1 reads h1 via tabH[deg[n]] (HTAB). Last node fuses decoder st.1.
    for (int d = 1; d < DBLK; ++d) {
        const f16* wd = wbuf + (size_t)d * 8 * HD * HD;
        if (d == 1)
            gn_edge<<<NEDGE / EM, 512, 0, stream>>>(
                tabP1, tabP2, ddegs, sdegs,
                wd + 2 * HD * HD, wd + 3 * HD * HD,
                eb16 + (size_t)d * HD, p_eb2 + (size_t)d * HD,
                p_elng + (size_t)d * HD, p_elnb + (size_t)d * HD, msg);
        else
            gn_edge<<<NEDGE / EM, 512, 0, stream>>>(
                P1, P2, dsorted, ssorted,
                wd + 2 * HD * HD, wd + 3 * HD * HD,
                eb16 + (size_t)d * HD, p_eb2 + (size_t)d * HD,
                p_elng + (size_t)d * HD, p_elnb + (size_t)d * HD, msg);
        if (d == 1) {
            const f16* wn = wbuf + (size_t)(d + 1) * 8 * HD * HD;
            gn_node<1, true, false, true><<<NTOT / 64, 256, 0, stream>>>(
                h16, msg, rowptr, deg, nullptr, nullptr, tabH,
                wd + 4 * HD * HD, wd + 5 * HD * HD, wd + 6 * HD * HD, wd + 7 * HD * HD,
                p_nb1 + (size_t)d * HD, p_nb2 + (size_t)d * HD,
                p_nlng + (size_t)d * HD, p_nlnb + (size_t)d * HD,
                wn + 0 * HD * HD, wn + 1 * HD * HD, P1, P2, nullptr, nullptr);
        } else if (d < DBLK - 1) {
            const f16* wn = wbuf + (size_t)(d + 1) * 8 * HD * HD;
            gn_node<1, true, false, false><<<NTOT / 64, 256, 0, stream>>>(
                h16, msg, rowptr, deg, nullptr, nullptr, nullptr,
                wd + 4 * HD * HD, wd + 5 * HD * HD, wd + 6 * HD * HD, wd + 7 * HD * HD,
                p_nb1 + (size_t)d * HD, p_nb2 + (size_t)d * HD,
                p_nlng + (size_t)d * HD, p_nlnb + (size_t)d * HD,
                wn + 0 * HD * HD, wn + 1 * HD * HD, P1, P2, nullptr, nullptr);
        } else {
            gn_node<1, false, true, false><<<NTOT / 64, 256, 0, stream>>>(
                h16, msg, rowptr, deg, nullptr, nullptr, nullptr,
                wd + 4 * HD * HD, wd + 5 * HD * HD, wd + 6 * HD * HD, wd + 7 * HD * HD,
                p_nb1 + (size_t)d * HD, p_nb2 + (size_t)d * HD,
                p_nlng + (size_t)d * HD, p_nlnb + (size_t)d * HD,
                wbuf, wbuf, P1, P2, dwt, uval);
        }
    }

    // ---- Decoder stage 2 only (stage 1 fused into the last node)
    dec_gather_out<<<(NMESH + 3) / 4, 256, 0, stream>>>(
        uval, mrow, mdeg, mslot, dec_cw1, dec_cb1, dec_cw2, dec_cb2, dec_cw3,
        (float*)d_out, NMESH);
}

// Round 10
// 564.678 us; speedup vs baseline: 1.1153x; 1.1153x over previous
//
#include <hip/hip_runtime.h>
#include <hip/hip_fp16.h>
#include <math.h>

// Problem constants (from reference)
#define BS    8
#define NE    4800
#define NN    4981
#define CIN   3
#define HD    128      // H
#define DBLK  6        // D processor blocks
#define NEDGE 153600   // BS*EPG
#define NTOT  38400    // BS*NE (graph nodes)
#define NMESH (BS*NN)  // 39848 mesh rows
#define NNP   5120     // NN padded to 20*256 for scan
#define EM    128      // edge-kernel tile rows
#define TROWS 256      // deg-table rows (max supported degree + 1)

// transposed decoder-weight table offsets (floats)
#define UW1T  0
#define UB1T  512
#define UW2T  1024
#define UB2T  3072
#define UW3T  3584
#define ULNGT 5632
#define ULNBT 6144
#define DWT_N 6656

typedef _Float16 f16;
typedef _Float16 f16x8 __attribute__((ext_vector_type(8)));
typedef float f32x4 __attribute__((ext_vector_type(4)));

__device__ __forceinline__ float lrelu(float x) { return x >= 0.0f ? x : 0.2f * x; }

// ---------------------------------------------------------------------------
// K0 (fused): hv0 = ln(mlp(enc_clnb_row, enc_ew1..3)) then
// m0 = ln(mlp([hv0;hv0]), elng0, elnb0).
// ---------------------------------------------------------------------------
__global__ __launch_bounds__(128)
void enc_msg0_kernel(const float* __restrict__ clnb,
                     const float* __restrict__ ew1, const float* __restrict__ eb1,
                     const float* __restrict__ ew2, const float* __restrict__ eb2,
                     const float* __restrict__ ew3,
                     const float* __restrict__ g, const float* __restrict__ b,
                     float* __restrict__ hv0,
                     const float* __restrict__ pew1, const float* __restrict__ peb1,
                     const float* __restrict__ pew2, const float* __restrict__ peb2,
                     const float* __restrict__ pew3,
                     const float* __restrict__ pg, const float* __restrict__ pb,
                     float* __restrict__ m0) {
    __shared__ float s1[HD], s2[HD], s3[HD], hv[HD];
    int j = threadIdx.x;
    // ---- encoder-constant part
    float a = eb1[j];
    for (int c = 0; c < CIN; ++c) a += clnb[c] * ew1[c * HD + j];
    s1[j] = lrelu(a);
    __syncthreads();
    a = eb2[j];
    for (int k = 0; k < HD; ++k) a += s1[k] * ew2[k * HD + j];
    s2[j] = lrelu(a);
    __syncthreads();
    a = 0.0f;
    for (int k = 0; k < HD; ++k) a += s2[k] * ew3[k * HD + j];
    s3[j] = a;
    __syncthreads();
    float m = 0.0f;
    for (int k = 0; k < HD; ++k) m += s3[k];
    m *= (1.0f / HD);
    float v = 0.0f;
    for (int k = 0; k < HD; ++k) { float d = s3[k] - m; v += d * d; }
    v *= (1.0f / HD);
    float rs = 1.0f / sqrtf(v + 1e-5f);
    float h0 = (s3[j] - m) * rs * g[j] + b[j];
    hv0[j] = h0;
    hv[j] = h0;
    __syncthreads();
    // ---- msg0 part (reads hv from LDS)
    a = peb1[j];
    for (int k = 0; k < HD; ++k) a += hv[k] * (pew1[k * HD + j] + pew1[(k + HD) * HD + j]);
    s1[j] = lrelu(a);
    __syncthreads();
    a = peb2[j];
    for (int k = 0; k < HD; ++k) a += s1[k] * pew2[k * HD + j];
    s2[j] = lrelu(a);
    __syncthreads();
    a = 0.0f;
    for (int k = 0; k < HD; ++k) a += s2[k] * pew3[k * HD + j];
    s3[j] = a;
    __syncthreads();
    m = 0.0f;
    for (int k = 0; k < HD; ++k) m += s3[k];
    m *= (1.0f / HD);
    v = 0.0f;
    for (int k = 0; k < HD; ++k) { float d = s3[k] - m; v += d * d; }
    v *= (1.0f / HD);
    rs = 1.0f / sqrtf(v + 1e-5f);
    m0[j] = (s3[j] - m) * rs * pg[j] + pb[j];
}

// ---------------------------------------------------------------------------
// Convert + transpose processor weights to f16 Wt[n][k]; block 48 = f16 copy
// of edge L1 biases + deg-iota init (R10); block 49 = decoder weight
// transpose (in prologue; dwt has a dedicated region).
// ---------------------------------------------------------------------------
__global__ __launch_bounds__(256)
void conv_all_kernel(const float* __restrict__ ew1, const float* __restrict__ ew2,
                     const float* __restrict__ ew3,
                     const float* __restrict__ nw1, const float* __restrict__ nw2,
                     const float* __restrict__ nw3, f16* __restrict__ wbuf,
                     const float* __restrict__ eb1, f16* __restrict__ eb16,
                     const float* __restrict__ uw1, const float* __restrict__ ub1,
                     const float* __restrict__ uw2, const float* __restrict__ ub2,
                     const float* __restrict__ uw3, const float* __restrict__ ulng,
                     const float* __restrict__ ulnb, float* __restrict__ dwt,
                     int* __restrict__ degIota) {
    int b = blockIdx.x;        // 0..49
    int tid = threadIdx.x;
    if (b == 48) {
        for (int i = tid; i < DBLK * HD; i += 256)
            eb16[i] = (f16)eb1[i];
        degIota[tid] = tid;     // 256 threads = TROWS
        return;
    }
    if (b == 49) {
        for (int idx = tid; idx < 512; idx += 256) {
            int o = idx >> 7, c = idx & 127;
            dwt[UW1T + idx] = uw1[c * 4 + o];
            dwt[UB1T + idx] = ub1[c * 4 + o];
            dwt[UB2T + idx] = ub2[c * 4 + o];
            dwt[ULNGT + idx] = ulng[c * 4 + o];
            dwt[ULNBT + idx] = ulnb[c * 4 + o];
        }
        for (int idx = tid; idx < 2048; idx += 256) {
            int io = idx >> 7, c = idx & 127;
            dwt[UW2T + idx] = uw2[c * 16 + io];
            dwt[UW3T + idx] = uw3[c * 16 + io];
        }
        return;
    }
    int d = b >> 3, m = b & 7;
    const float* src;
    switch (m) {
        case 0: src = ew1 + (size_t)d * 2 * HD * HD; break;
        case 1: src = ew1 + (size_t)d * 2 * HD * HD + HD * HD; break;
        case 2: src = ew2 + (size_t)d * HD * HD; break;
        case 3: src = ew3 + (size_t)d * HD * HD; break;
        case 4: src = nw1 + (size_t)d * 2 * HD * HD; break;
        case 5: src = nw1 + (size_t)d * 2 * HD * HD + HD * HD; break;
        case 6: src = nw2 + (size_t)d * HD * HD; break;
        default: src = nw3 + (size_t)d * HD * HD; break;
    }
    f16* out = wbuf + (size_t)b * HD * HD;
    for (int idx = tid; idx < HD * HD; idx += 256) {
        int n = idx >> 7, k = idx & 127;
        out[idx] = (f16)src[k * HD + n];   // Wt[n][k] = W[k][n]
    }
}

// ---------------------------------------------------------------------------
// Fused CSR build (counting sort), edge graph (by dest) + mesh (by conn) in
// single grids. Mesh arrays in a DEDICATED region (R5 lesson).
// ---------------------------------------------------------------------------
#define EHB (NEDGE / 256)     // 600 edge hist blocks
#define MHB (NE * 4 / 256)    // 75 mesh hist blocks
#define ESB (NTOT / 256)      // 150 edge scan blocks
#define MSB (NNP / 256)       // 20 mesh scan blocks

__global__ __launch_bounds__(256)
void prep_hist(const int* __restrict__ e_dst, const int* __restrict__ conn,
               int* __restrict__ deg, int* __restrict__ mdeg) {
    int b = blockIdx.x;
    if (b < EHB) {
        int e = b * 256 + threadIdx.x;
        atomicAdd(&deg[e_dst[e]], 1);
    } else {
        int idx = (b - EHB) * 256 + threadIdx.x;   // < 19200 exact
        atomicAdd(&mdeg[conn[idx]], 1);
    }
}

__device__ __forceinline__ void scan1_body(const int* __restrict__ deg,
                                           int* __restrict__ rowptr,
                                           int* __restrict__ bsum, int bi) {
    __shared__ int s[256];
    int i = bi * 256 + threadIdx.x;
    int v = deg[i];
    s[threadIdx.x] = v;
    __syncthreads();
    for (int off = 1; off < 256; off <<= 1) {
        int t = (threadIdx.x >= off) ? s[threadIdx.x - off] : 0;
        __syncthreads();
        s[threadIdx.x] += t;
        __syncthreads();
    }
    rowptr[i] = s[threadIdx.x] - v;          // exclusive
    if (threadIdx.x == 255) bsum[bi] = s[255];
}

__global__ __launch_bounds__(256)
void prep_scan1(const int* __restrict__ deg, int* __restrict__ rowptr,
                int* __restrict__ bsum,
                const int* __restrict__ mdeg, int* __restrict__ mrow,
                int* __restrict__ mbsum) {
    int b = blockIdx.x;
    if (b < ESB) scan1_body(deg, rowptr, bsum, b);
    else         scan1_body(mdeg, mrow, mbsum, b - ESB);
}

__device__ __forceinline__ void scan2_body(int* __restrict__ bsum, int nb) {
    __shared__ int s[256];
    int v = (threadIdx.x < nb) ? bsum[threadIdx.x] : 0;
    s[threadIdx.x] = v;
    __syncthreads();
    for (int off = 1; off < 256; off <<= 1) {
        int t = (threadIdx.x >= off) ? s[threadIdx.x - off] : 0;
        __syncthreads();
        s[threadIdx.x] += t;
        __syncthreads();
    }
    if (threadIdx.x < nb) bsum[threadIdx.x] = s[threadIdx.x] - v;   // exclusive
}

__global__ __launch_bounds__(256)
void prep_scan2(int* __restrict__ bsum, int* __restrict__ mbsum) {
    if (blockIdx.x == 0) scan2_body(bsum, ESB);
    else                 scan2_body(mbsum, MSB);
}

__global__ __launch_bounds__(256)
void prep_scan3(int* __restrict__ rowptr, const int* __restrict__ bsum,
                int* __restrict__ mrow, const int* __restrict__ mbsum) {
    int b = blockIdx.x;
    if (b < ESB) {
        int i = b * 256 + threadIdx.x;
        rowptr[i] += bsum[b];
    } else {
        int i = (b - ESB) * 256 + threadIdx.x;
        mrow[i] += mbsum[b - ESB];
    }
}

// R10: edge branch additionally emits per-edge DEST/SRC degrees so the d=1
// edge kernel can gather from the 256-row deg tables with zero code change.
__global__ __launch_bounds__(256)
void prep_scatter(const int* __restrict__ dest, const int* __restrict__ srcv,
                  const int* __restrict__ rowptr, int* __restrict__ cursor,
                  int* __restrict__ dsorted, int* __restrict__ ssorted,
                  const int* __restrict__ conn, const int* __restrict__ mrow,
                  int* __restrict__ mcur, int* __restrict__ mslot,
                  const int* __restrict__ deg,
                  int* __restrict__ ddegs, int* __restrict__ sdegs) {
    int b = blockIdx.x;
    if (b < EHB) {
        int e = b * 256 + threadIdx.x;
        int d = dest[e];
        int s = srcv[e];
        int pos = rowptr[d] + atomicAdd(&cursor[d], 1);
        dsorted[pos] = d;
        ssorted[pos] = s;
        ddegs[pos] = deg[d];
        sdegs[pos] = deg[s];
    } else {
        int idx = (b - EHB) * 256 + threadIdx.x;   // < 19200 exact
        int nd = conn[idx];
        int pos = mrow[nd] + atomicAdd(&mcur[nd], 1);
        mslot[pos] = idx;
    }
}

// ---------------------------------------------------------------------------
// Shared GEMM helpers (R0 structure — all skeleton edits measured neutral-to-
// negative in rounds 1-4).
// ---------------------------------------------------------------------------
template <int NT>
__device__ __forceinline__ void stage_w(const f16* __restrict__ Wg, f16 (*Bt)[HD + 8],
                                        int tid) {
    #pragma unroll
    for (int t = 0; t < 2048 / NT; ++t) {
        int idx = tid + t * NT;             // 16B chunks of 128x128 f16
        int r = idx >> 4, c = (idx & 15) * 8;
        *(uint4*)(&Bt[r][c]) = *(const uint4*)(Wg + (size_t)r * HD + c);
    }
}

__device__ __forceinline__ void mfma_pass(const f16 (*A)[HD + 8], const f16 (*Bt)[HD + 8],
                                          int rt_base, int ct_base, int ln, int quad,
                                          f32x4 acc[2][4]) {
    #pragma unroll
    for (int ks = 0; ks < 4; ++ks) {
        int kb = ks * 32 + quad * 8;
        f16x8 a0 = *(const f16x8*)(&A[rt_base + ln][kb]);
        f16x8 a1 = *(const f16x8*)(&A[rt_base + 16 + ln][kb]);
        #pragma unroll
        for (int c = 0; c < 4; ++c) {
            f16x8 b = *(const f16x8*)(&Bt[ct_base + c * 16 + ln][kb]);
            acc[0][c] = __builtin_amdgcn_mfma_f32_16x16x32_f16(a0, b, acc[0][c], 0, 0, 0);
            acc[1][c] = __builtin_amdgcn_mfma_f32_16x16x32_f16(a1, b, acc[1][c], 0, 0, 0);
        }
    }
}

// ---------------------------------------------------------------------------
// Edge kernel (d>=1), dest-sorted, M=128 tile, 512 threads (8 waves).
// Direct per-thread global index loads (R7). For d=1 the caller passes the
// deg TABLES as P1/P2 and per-edge degrees as the index arrays (R10) — the
// kernel itself is unchanged.
// ---------------------------------------------------------------------------
__global__ __launch_bounds__(512, 4)
void gn_edge(const f16* __restrict__ P1, const f16* __restrict__ P2,
             const int* __restrict__ dsorted, const int* __restrict__ ssorted,
             const f16* __restrict__ W2, const f16* __restrict__ W3,
             const f16* __restrict__ b1h, const float* __restrict__ b2,
             const float* __restrict__ g, const float* __restrict__ bln,
             f16* __restrict__ msg) {
    __shared__ __align__(16) f16 As[EM][HD + 8];
    __shared__ __align__(16) f16 Bt[HD][HD + 8];
    __shared__ float red[EM][2][2];

    const int tid = threadIdx.x;
    const int base = blockIdx.x * EM;
    const int wave = tid >> 6, lane = tid & 63;
    const int ln = lane & 15, quad = lane >> 4;
    const int rt_base = (wave >> 1) * 32;     // 0,32,64,96
    const int ct_base = (wave & 1) * 64;
    const int half = wave & 1;
    const int r0 = tid >> 4;                  // gather row (+32*it)
    const int cg = (tid & 15) * 8;            // gather col

    const f16 k02s = (f16)0.2f;
    const f16x8 k02 = {k02s, k02s, k02s, k02s, k02s, k02s, k02s, k02s};

    // direct per-thread index loads (no LDS, no barrier)
    int dI[4], sI[4];
    #pragma unroll
    for (int it = 0; it < 4; ++it) {
        dI[it] = dsorted[base + r0 + it * 32];
        sI[it] = ssorted[base + r0 + it * 32];
    }
    stage_w<512>(W2, Bt, tid);
    const f16x8 bb = *(const f16x8*)(b1h + cg);
    #pragma unroll
    for (int it = 0; it < 4; ++it) {
        f16x8 p1 = *(const f16x8*)(P1 + (size_t)dI[it] * HD + cg);
        f16x8 p2 = *(const f16x8*)(P2 + (size_t)sI[it] * HD + cg);
        f16x8 s = p1 + p2 + bb;             // v_pk_add_f16
        *(f16x8*)(&As[r0 + it * 32][cg]) = __builtin_elementwise_max(s, s * k02);
    }
    __syncthreads();

    f32x4 acc[2][4];

    // ---- Layer 2
    #pragma unroll
    for (int c = 0; c < 4; ++c) {
        float bj = b2[ct_base + c * 16 + ln];
        f32x4 bv = {bj, bj, bj, bj};
        acc[0][c] = bv; acc[1][c] = bv;
    }
    mfma_pass(As, Bt, rt_base, ct_base, ln, quad, acc);
    __syncthreads();
    stage_w<512>(W3, Bt, tid);
    #pragma unroll
    for (int i = 0; i < 2; ++i)
        #pragma unroll
        for (int c = 0; c < 4; ++c)
            #pragma unroll
            for (int r = 0; r < 4; ++r)
                As[rt_base + i * 16 + quad * 4 + r][ct_base + c * 16 + ln] =
                    (f16)lrelu(acc[i][c][r]);
    __syncthreads();

    // ---- Layer 3
    #pragma unroll
    for (int c = 0; c < 4; ++c) { f32x4 z = {0,0,0,0}; acc[0][c] = z; acc[1][c] = z; }
    mfma_pass(As, Bt, rt_base, ct_base, ln, quad, acc);

    // ---- LayerNorm stats
    #pragma unroll
    for (int i = 0; i < 2; ++i)
        #pragma unroll
        for (int r = 0; r < 4; ++r) {
            float s = acc[i][0][r] + acc[i][1][r] + acc[i][2][r] + acc[i][3][r];
            float q = acc[i][0][r] * acc[i][0][r] + acc[i][1][r] * acc[i][1][r] +
                      acc[i][2][r] * acc[i][2][r] + acc[i][3][r] * acc[i][3][r];
            s += __shfl_xor(s, 1); q += __shfl_xor(q, 1);
            s += __shfl_xor(s, 2); q += __shfl_xor(q, 2);
            s += __shfl_xor(s, 4); q += __shfl_xor(q, 4);
            s += __shfl_xor(s, 8); q += __shfl_xor(q, 8);
            if (ln == 0) {
                int row = rt_base + i * 16 + quad * 4 + r;
                red[row][half][0] = s;
                red[row][half][1] = q;
            }
        }
    __syncthreads();

    // ---- Epilogue: LN scale + plain f16 store to msg (sorted slot order)
    float gv[4], bv[4];
    #pragma unroll
    for (int c = 0; c < 4; ++c) {
        int col = ct_base + c * 16 + ln;
        gv[c] = g[col]; bv[c] = bln[col];
    }
    #pragma unroll
    for (int i = 0; i < 2; ++i)
        #pragma unroll
        for (int r = 0; r < 4; ++r) {
            int row = rt_base + i * 16 + quad * 4 + r;
            float s = red[row][0][0] + red[row][1][0];
            float q = red[row][0][1] + red[row][1][1];
            float m = s * (1.0f / HD);
            float var = q * (1.0f / HD) - m * m;
            float rs = 1.0f / sqrtf(var + 1e-5f);
            #pragma unroll
            for (int c = 0; c < 4; ++c) {
                int col = ct_base + c * 16 + ln;
                float v = (acc[i][c][r] - m) * rs * gv[c] + bv[c];
                msg[(size_t)(base + row) * HD + col] = (f16)v;
            }
        }
}

// ---------------------------------------------------------------------------
// Node kernel — R8-exact structure (64-row As, 256 threads, 3 blocks/CU):
//  * aggr msg-sum unrolled by 4 (R6); direct rowptr/deg loads (R7);
//  * AGGR==0 hreg from hv0 (R7) — doubles as the deg-TABLE builder (R10):
//    4 blocks + iota deg array produce tabH/tabP1/tabP2 rows bit-identical
//    to the old 600-block node0 output;
//  * HTAB (R10): node d=1 reads hreg via tabH[deg[n]] instead of h16;
//  * DECF (R8-exact): fused decoder stage 1, scattered dwt reads (the R9
//    dwt->LDS restage measured +21us/dispatch with FETCH 25->56MB — reverted);
//  * PROD tail R8-exact (stage_w; R9's T14-wr[8] suspected occupancy cost —
//    reverted).
// ---------------------------------------------------------------------------
template <int AGGR, bool PROD, bool DECF, bool HTAB>
__global__ __launch_bounds__(256, 3)
void gn_node(f16* __restrict__ h16, const f16* __restrict__ msg,
             const int* __restrict__ rowptr, const int* __restrict__ deg,
             const float* __restrict__ m0, const float* __restrict__ hv0,
             const f16* __restrict__ htab,
             const f16* __restrict__ W1a, const f16* __restrict__ W1b,
             const f16* __restrict__ W2, const f16* __restrict__ W3,
             const float* __restrict__ b1, const float* __restrict__ b2,
             const float* __restrict__ g, const float* __restrict__ bln,
             const f16* __restrict__ nW1a, const f16* __restrict__ nW1b,
             f16* __restrict__ P1, f16* __restrict__ P2,
             const float* __restrict__ dwt, f16* __restrict__ uval) {
    __shared__ __align__(16) f16 As[64][HD + 8];
    __shared__ __align__(16) f16 Bt[HD][HD + 8];
    __shared__ float red[64][2][2];

    const int tid = threadIdx.x;
    const int base = blockIdx.x * 64;
    const int wave = tid >> 6, lane = tid & 63;
    const int ln = lane & 15, quad = lane >> 4;
    const int rt_base = (wave >> 1) * 32;
    const int ct_base = (wave & 1) * 64;
    const int half = wave & 1;

    // ---- Stage: aggr -> As, h -> hreg (VGPRs). Direct index loads (no LDS).
    f16x8 hreg[4];
    #pragma unroll
    for (int t = 0; t < 4; ++t) {
        int r = (tid >> 4) + t * 16;        // 0..63
        int c = (tid & 15) * 8;
        if (AGGR == 0) {
            f16x8 hz;
            #pragma unroll
            for (int u = 0; u < 8; ++u) hz[u] = (f16)hv0[c + u];
            hreg[t] = hz;
            float sc = (float)deg[base + r];
            f16x8 o;
            #pragma unroll
            for (int u = 0; u < 8; ++u) o[u] = (f16)(sc * m0[c + u]);
            *(f16x8*)(&As[r][c]) = o;
        } else {
            if (HTAB)
                hreg[t] = *(const f16x8*)(htab + (size_t)deg[base + r] * HD + c);
            else
                hreg[t] = *(const f16x8*)(h16 + (size_t)(base + r) * HD + c);
            int rp = rowptr[base + r], dg = deg[base + r];
            float a[8] = {0, 0, 0, 0, 0, 0, 0, 0};
            int j = 0;
            for (; j + 4 <= dg; j += 4) {   // 4 independent loads in flight
                f16x8 v0 = *(const f16x8*)(msg + (size_t)(rp + j) * HD + c);
                f16x8 v1 = *(const f16x8*)(msg + (size_t)(rp + j + 1) * HD + c);
                f16x8 v2 = *(const f16x8*)(msg + (size_t)(rp + j + 2) * HD + c);
                f16x8 v3 = *(const f16x8*)(msg + (size_t)(rp + j + 3) * HD + c);
                #pragma unroll
                for (int u = 0; u < 8; ++u)
                    a[u] += ((float)v0[u] + (float)v1[u]) + ((float)v2[u] + (float)v3[u]);
            }
            for (; j < dg; ++j) {
                f16x8 mv = *(const f16x8*)(msg + (size_t)(rp + j) * HD + c);
                #pragma unroll
                for (int u = 0; u < 8; ++u) a[u] += (float)mv[u];
            }
            f16x8 o;
            #pragma unroll
            for (int u = 0; u < 8; ++u) o[u] = (f16)a[u];
            *(f16x8*)(&As[r][c]) = o;
        }
    }
    stage_w<256>(W1b, Bt, tid);
    __syncthreads();

    f32x4 acc[2][4];
    #pragma unroll
    for (int c = 0; c < 4; ++c) {
        float bj = b1[ct_base + c * 16 + ln];
        f32x4 bb = {bj, bj, bj, bj};
        acc[0][c] = bb; acc[1][c] = bb;
    }
    mfma_pass(As, Bt, rt_base, ct_base, ln, quad, acc);   // aggr @ W1b
    __syncthreads();

    #pragma unroll
    for (int t = 0; t < 4; ++t) {
        int r = (tid >> 4) + t * 16;
        int c = (tid & 15) * 8;
        *(f16x8*)(&As[r][c]) = hreg[t];
    }
    stage_w<256>(W1a, Bt, tid);
    __syncthreads();
    mfma_pass(As, Bt, rt_base, ct_base, ln, quad, acc);   // + h @ W1a
    __syncthreads();

    stage_w<256>(W2, Bt, tid);
    #pragma unroll
    for (int i = 0; i < 2; ++i)
        #pragma unroll
        for (int c = 0; c < 4; ++c)
            #pragma unroll
            for (int r = 0; r < 4; ++r)
                As[rt_base + i * 16 + quad * 4 + r][ct_base + c * 16 + ln] =
                    (f16)lrelu(acc[i][c][r]);
    __syncthreads();

    #pragma unroll
    for (int c = 0; c < 4; ++c) {
        float bj = b2[ct_base + c * 16 + ln];
        f32x4 bb = {bj, bj, bj, bj};
        acc[0][c] = bb; acc[1][c] = bb;
    }
    mfma_pass(As, Bt, rt_base, ct_base, ln, quad, acc);   // act1 @ W2
    __syncthreads();
    stage_w<256>(W3, Bt, tid);
    #pragma unroll
    for (int i = 0; i < 2; ++i)
        #pragma unroll
        for (int c = 0; c < 4; ++c)
            #pragma unroll
            for (int r = 0; r < 4; ++r)
                As[rt_base + i * 16 + quad * 4 + r][ct_base + c * 16 + ln] =
                    (f16)lrelu(acc[i][c][r]);
    __syncthreads();

    #pragma unroll
    for (int c = 0; c < 4; ++c) { f32x4 z = {0,0,0,0}; acc[0][c] = z; acc[1][c] = z; }
    mfma_pass(As, Bt, rt_base, ct_base, ln, quad, acc);   // act2 @ W3

    // ---- LayerNorm stats
    #pragma unroll
    for (int i = 0; i < 2; ++i)
        #pragma unroll
        for (int r = 0; r < 4; ++r) {
            float s = acc[i][0][r] + acc[i][1][r] + acc[i][2][r] + acc[i][3][r];
            float q = acc[i][0][r] * acc[i][0][r] + acc[i][1][r] * acc[i][1][r] +
                      acc[i][2][r] * acc[i][2][r] + acc[i][3][r] * acc[i][3][r];
            s += __shfl_xor(s, 1); q += __shfl_xor(q, 1);
            s += __shfl_xor(s, 2); q += __shfl_xor(q, 2);
            s += __shfl_xor(s, 4); q += __shfl_xor(q, 4);
            s += __shfl_xor(s, 8); q += __shfl_xor(q, 8);
            if (ln == 0) {
                int row = rt_base + i * 16 + quad * 4 + r;
                red[row][half][0] = s;
                red[row][half][1] = q;
            }
        }
    __syncthreads();

    float gv[4], bv[4];
    #pragma unroll
    for (int c = 0; c < 4; ++c) {
        int col = ct_base + c * 16 + ln;
        gv[c] = g[col]; bv[c] = bln[col];
    }

    if (!DECF) {
        #pragma unroll
        for (int i = 0; i < 2; ++i)
            #pragma unroll
            for (int r = 0; r < 4; ++r) {
                int row = rt_base + i * 16 + quad * 4 + r;
                float s = red[row][0][0] + red[row][1][0];
                float q = red[row][0][1] + red[row][1][1];
                float m = s * (1.0f / HD);
                float var = q * (1.0f / HD) - m * m;
                float rs = 1.0f / sqrtf(var + 1e-5f);
                #pragma unroll
                for (int c = 0; c < 4; ++c) {
                    int col = ct_base + c * 16 + ln;
                    float v = (acc[i][c][r] - m) * rs * gv[c] + bv[c];
                    f16 hv = (f16)v;
                    h16[(size_t)(base + row) * HD + col] = hv;
                    if (PROD) As[row][col] = hv;    // h_new for P production
                }
            }
    } else {
        // ---- Fused decoder stage 1 (R8-exact): per element h(row,col),
        // upsample MLP 1->4->4->4 + LN(4), write 4 f16 to uval.
        float mm[2][4], rr[2][4];
        #pragma unroll
        for (int i = 0; i < 2; ++i)
            #pragma unroll
            for (int r = 0; r < 4; ++r) {
                int row = rt_base + i * 16 + quad * 4 + r;
                float s = red[row][0][0] + red[row][1][0];
                float q = red[row][0][1] + red[row][1][1];
                float m = s * (1.0f / HD);
                float var = q * (1.0f / HD) - m * m;
                mm[i][r] = m;
                rr[i][r] = 1.0f / sqrtf(var + 1e-5f);
            }
        #pragma unroll
        for (int c = 0; c < 4; ++c) {
            int col = ct_base + c * 16 + ln;
            float w1v[4], wb1[4], wb2[4], lg4[4], lb4[4];
            #pragma unroll
            for (int o = 0; o < 4; ++o) {
                w1v[o] = dwt[UW1T + o * 128 + col];
                wb1[o] = dwt[UB1T + o * 128 + col];
                wb2[o] = dwt[UB2T + o * 128 + col];
                lg4[o] = dwt[ULNGT + o * 128 + col];
                lb4[o] = dwt[ULNBT + o * 128 + col];
            }
            float w2v[16], w3v[16];
            #pragma unroll
            for (int io = 0; io < 16; ++io) {
                w2v[io] = dwt[UW2T + io * 128 + col];
                w3v[io] = dwt[UW3T + io * 128 + col];
            }
            #pragma unroll
            for (int i = 0; i < 2; ++i)
                #pragma unroll
                for (int r = 0; r < 4; ++r) {
                    int row = rt_base + i * 16 + quad * 4 + r;
                    float v = (acc[i][c][r] - mm[i][r]) * rr[i][r] * gv[c] + bv[c];
                    float s = (float)(f16)v;     // match h16 rounding
                    float u1[4], u2[4], u3[4];
                    #pragma unroll
                    for (int o = 0; o < 4; ++o)
                        u1[o] = lrelu(s * w1v[o] + wb1[o]);
                    #pragma unroll
                    for (int o = 0; o < 4; ++o) {
                        float a = wb2[o];
                        #pragma unroll
                        for (int i2 = 0; i2 < 4; ++i2) a += u1[i2] * w2v[i2 * 4 + o];
                        u2[o] = lrelu(a);
                    }
                    #pragma unroll
                    for (int o = 0; o < 4; ++o) {
                        float a = 0.f;
                        #pragma unroll
                        for (int i2 = 0; i2 < 4; ++i2) a += u2[i2] * w3v[i2 * 4 + o];
                        u3[o] = a;
                    }
                    float m4 = 0.25f * (u3[0] + u3[1] + u3[2] + u3[3]);
                    float var4 = 0.f;
                    #pragma unroll
                    for (int o = 0; o < 4; ++o) { float d = u3[o] - m4; var4 += d * d; }
                    var4 *= 0.25f;
                    float rs4 = 1.0f / sqrtf(var4 + 1e-5f);
                    size_t ub = (size_t)(base + row) * 4 * HD + col;
                    #pragma unroll
                    for (int o = 0; o < 4; ++o)
                        uval[ub + (size_t)o * HD] =
                            (f16)((u3[o] - m4) * rs4 * lg4[o] + lb4[o]);
                }
        }
    }

    if (PROD) {
        __syncthreads();                 // h_new in As visible
        stage_w<256>(nW1a, Bt, tid);
        __syncthreads();
        #pragma unroll
        for (int c = 0; c < 4; ++c) { f32x4 z = {0,0,0,0}; acc[0][c] = z; acc[1][c] = z; }
        mfma_pass(As, Bt, rt_base, ct_base, ln, quad, acc);
        #pragma unroll
        for (int i = 0; i < 2; ++i)
            #pragma unroll
            for (int c = 0; c < 4; ++c)
                #pragma unroll
                for (int r = 0; r < 4; ++r)
                    P1[(size_t)(base + rt_base + i * 16 + quad * 4 + r) * HD +
                       ct_base + c * 16 + ln] = (f16)acc[i][c][r];
        __syncthreads();
        stage_w<256>(nW1b, Bt, tid);
        __syncthreads();
        #pragma unroll
        for (int c = 0; c < 4; ++c) { f32x4 z = {0,0,0,0}; acc[0][c] = z; acc[1][c] = z; }
        mfma_pass(As, Bt, rt_base, ct_base, ln, quad, acc);
        #pragma unroll
        for (int i = 0; i < 2; ++i)
            #pragma unroll
            for (int c = 0; c < 4; ++c)
                #pragma unroll
                for (int r = 0; r < 4; ++r)
                    P2[(size_t)(base + rt_base + i * 16 + quad * 4 + r) * HD +
                       ct_base + c * 16 + ln] = (f16)acc[i][c][r];
    }
}

// ---------------------------------------------------------------------------
// Decoder stage 2 (fused gather + output MLP): one wave per mesh row.
// Degree loop unrolled by 4 (R8).
// ---------------------------------------------------------------------------
__global__ __launch_bounds__(256)
void dec_gather_out(const f16* __restrict__ uval,
                    const int* __restrict__ mrow, const int* __restrict__ mdeg,
                    const int* __restrict__ mslot,
                    const float* __restrict__ cw1, const float* __restrict__ cb1,
                    const float* __restrict__ cw2, const float* __restrict__ cb2,
                    const float* __restrict__ cw3,
                    float* __restrict__ o, int nrows) {
    int r = blockIdx.x * 4 + (threadIdx.x >> 6);
    if (r >= nrows) return;
    int lane = threadIdx.x & 63;
    int b = r / NN, n = r - b * NN;
    int rp = mrow[n], dg = mdeg[n];
    size_t boff = (size_t)b * NE * 4;
    float a0 = 0.f, a1 = 0.f;
    int j = 0;
    for (; j + 4 <= dg; j += 4) {
        int s0 = mslot[rp + j], s1 = mslot[rp + j + 1];
        int s2 = mslot[rp + j + 2], s3 = mslot[rp + j + 3];
        const f16* u0 = uval + (boff + s0) * HD + lane * 2;
        const f16* u1 = uval + (boff + s1) * HD + lane * 2;
        const f16* u2 = uval + (boff + s2) * HD + lane * 2;
        const f16* u3 = uval + (boff + s3) * HD + lane * 2;
        float b00 = (float)u0[0], b01 = (float)u0[1];
        float b10 = (float)u1[0], b11 = (float)u1[1];
        float b20 = (float)u2[0], b21 = (float)u2[1];
        float b30 = (float)u3[0], b31 = (float)u3[1];
        a0 += (b00 + b10) + (b20 + b30);
        a1 += (b01 + b11) + (b21 + b31);
    }
    for (; j < dg; ++j) {
        int slot = mslot[rp + j];
        const f16* up = uval + (boff + slot) * HD + lane * 2;
        a0 += (float)up[0];
        a1 += (float)up[1];
    }
    int c0 = lane * 2, c1 = lane * 2 + 1;
    float s[3];
    #pragma unroll
    for (int k = 0; k < 3; ++k)
        s[k] = a0 * cw1[c0 * 3 + k] + a1 * cw1[c1 * 3 + k];
    #pragma unroll
    for (int off = 32; off >= 1; off >>= 1) {
        s[0] += __shfl_down(s[0], off);
        s[1] += __shfl_down(s[1], off);
        s[2] += __shfl_down(s[2], off);
    }
    if (lane == 0) {
        float t1[3], t2[3];
        #pragma unroll
        for (int k = 0; k < 3; ++k) t1[k] = lrelu(s[k] + cb1[k]);
        #pragma unroll
        for (int k = 0; k < 3; ++k) {
            float a = cb2[k];
            #pragma unroll
            for (int q = 0; q < 3; ++q) a += t1[q] * cw2[q * 3 + k];
            t2[k] = lrelu(a);
        }
        #pragma unroll
        for (int k = 0; k < 3; ++k) {
            float a = 0.f;
            #pragma unroll
            for (int q = 0; q < 3; ++q) a += t2[q] * cw3[q * 3 + k];
            o[(size_t)r * 3 + k] = a;
        }
    }
}

// ---------------------------------------------------------------------------
extern "C" void kernel_launch(void* const* d_in, const int* in_sizes, int n_in,
                              void* d_out, int out_size, void* d_ws, size_t ws_size,
                              hipStream_t stream) {
    const int* elem_conn = (const int*)d_in[1];
    const int* edge_index = (const int*)d_in[2];
    const int* e_src = edge_index;          // row 0
    const int* e_dst = edge_index + NEDGE;  // row 1
    const float* enc_clnb = (const float*)d_in[9];
    const float* enc_ew1 = (const float*)d_in[10];
    const float* enc_eb1 = (const float*)d_in[11];
    const float* enc_ew2 = (const float*)d_in[12];
    const float* enc_eb2 = (const float*)d_in[13];
    const float* enc_ew3 = (const float*)d_in[14];
    const float* enc_elng = (const float*)d_in[15];
    const float* enc_elnb = (const float*)d_in[16];
    const float* p_ew1 = (const float*)d_in[17];
    const float* p_eb1 = (const float*)d_in[18];
    const float* p_ew2 = (const float*)d_in[19];
    const float* p_eb2 = (const float*)d_in[20];
    const float* p_ew3 = (const float*)d_in[21];
    const float* p_elng = (const float*)d_in[22];
    const float* p_elnb = (const float*)d_in[23];
    const float* p_nw1 = (const float*)d_in[24];
    const float* p_nb1 = (const float*)d_in[25];
    const float* p_nw2 = (const float*)d_in[26];
    const float* p_nb2 = (const float*)d_in[27];
    const float* p_nw3 = (const float*)d_in[28];
    const float* p_nlng = (const float*)d_in[29];
    const float* p_nlnb = (const float*)d_in[30];
    const float* dec_uw1 = (const float*)d_in[31];
    const float* dec_ub1 = (const float*)d_in[32];
    const float* dec_uw2 = (const float*)d_in[33];
    const float* dec_ub2 = (const float*)d_in[34];
    const float* dec_uw3 = (const float*)d_in[35];
    const float* dec_ulng = (const float*)d_in[36];
    const float* dec_ulnb = (const float*)d_in[37];
    const float* dec_cw1 = (const float*)d_in[38];
    const float* dec_cb1 = (const float*)d_in[39];
    const float* dec_cw2 = (const float*)d_in[40];
    const float* dec_cb2 = (const float*)d_in[41];
    const float* dec_cw3 = (const float*)d_in[42];

    // Workspace layout (bytes), ~113 MB of the 256 MiB workspace.
    char* ws = (char*)d_ws;
    f16*   h16     = (f16*)(ws);                        //  9,830,400
    f16*   wbuf    = (f16*)(ws + 9830400);              //  1,572,864
    float* hv0     = (float*)(ws + 11403264);           //  512
    float* m0      = (float*)(ws + 11403776);           //  512
    f16*   P1      = (f16*)(ws + 11404288);             //  9,830,400
    f16*   P2      = (f16*)(ws + 21234688);             //  9,830,400
    f16*   msg     = (f16*)(ws + 31065088);             // 39,321,600
    int*   deg     = (int*)(ws + 70386688);             //  153,600
    int*   rowptr  = (int*)(ws + 70540288);             //  153,600
    int*   cursor  = (int*)(ws + 70693888);             //  153,600
    int*   bsum    = (int*)(ws + 70847488);             //  1,024
    int*   dsorted = (int*)(ws + 70848512);             //  614,400
    int*   ssorted = (int*)(ws + 71462912);             //  614,400
    f16*   eb16    = (f16*)(ws + 72077312);             //  1,536
    int*   mdeg    = (int*)(ws + 72078848);             //  20,480 (NNP)
    int*   mrow    = (int*)(ws + 72099328);             //  20,480
    int*   mcur    = (int*)(ws + 72119808);             //  20,480
    int*   mbsum   = (int*)(ws + 72140288);             //  1,024
    int*   mslot   = (int*)(ws + 72141312);             //  76,800
    float* dwt     = (float*)(ws + 72218112);           //  26,624
    f16*   uval    = (f16*)(ws + 72244736);             // 39,321,600
    int*   ddegs   = (int*)(ws + 111566336);            //  614,400
    int*   sdegs   = (int*)(ws + 112180736);            //  614,400
    f16*   tabH    = (f16*)(ws + 112795136);            //  65,536 (256x128)
    f16*   tabP1   = (f16*)(ws + 112860672);            //  65,536
    f16*   tabP2   = (f16*)(ws + 112926208);            //  65,536
    int*   degIota = (int*)(ws + 112991744);            //  1,024

    // ---- One memset for the CSR/meta region [deg .. mslot end) (R8-exact).
    hipMemsetAsync(deg, 0, 72218112 - 70386688, stream);

    // ---- Encoder constants + weight conversion (incl. decoder transpose)
    enc_msg0_kernel<<<1, 128, 0, stream>>>(
        enc_clnb, enc_ew1, enc_eb1, enc_ew2, enc_eb2, enc_ew3, enc_elng, enc_elnb, hv0,
        p_ew1, p_eb1, p_ew2, p_eb2, p_ew3, p_elng, p_elnb, m0);
    conv_all_kernel<<<50, 256, 0, stream>>>(p_ew1, p_ew2, p_ew3,
                                            p_nw1, p_nw2, p_nw3, wbuf, p_eb1, eb16,
                                            dec_uw1, dec_ub1, dec_uw2, dec_ub2,
                                            dec_uw3, dec_ulng, dec_ulnb, dwt,
                                            degIota);

    // ---- d=0 as a 256-row deg table (R10): same kernel, 4 blocks, iota degs.
    // Replaces the 600-block node0; rows bit-identical.
    {
        const f16* wd = wbuf;                       // d=0
        const f16* wn = wbuf + (size_t)8 * HD * HD; // d=1
        gn_node<0, true, false, false><<<TROWS / 64, 256, 0, stream>>>(
            tabH, nullptr, nullptr, degIota, m0, hv0, nullptr,
            wd + 4 * HD * HD, wd + 5 * HD * HD, wd + 6 * HD * HD, wd + 7 * HD * HD,
            p_nb1, p_nb2, p_nlng, p_nlnb,
            wn + 0 * HD * HD, wn + 1 * HD * HD, tabP1, tabP2, nullptr, nullptr);
    }

    // ---- Fused CSR builds: 5 dispatches (scatter also emits ddegs/sdegs).
    prep_hist<<<EHB + MHB, 256, 0, stream>>>(e_dst, elem_conn, deg, mdeg);
    prep_scan1<<<ESB + MSB, 256, 0, stream>>>(deg, rowptr, bsum, mdeg, mrow, mbsum);
    prep_scan2<<<2, 256, 0, stream>>>(bsum, mbsum);
    prep_scan3<<<ESB + MSB, 256, 0, stream>>>(rowptr, bsum, mrow, mbsum);
    prep_scatter<<<EHB + MHB, 256, 0, stream>>>(e_dst, e_src, rowptr, cursor,
                                                dsorted, ssorted,
                                                elem_conn, mrow, mcur, mslot,
                                                deg, ddegs, sdegs);

    // ---- d=1..5. Edge d=1 gathers from the deg tables (indices = degrees);
    // node d=1 reads h1 via tabH[deg[n]] (HTAB). Last node fuses decoder st.1.
    for (int d = 1; d < DBLK; ++d) {
        const f16* wd = wbuf + (size_t)d * 8 * HD * HD;
        if (d == 1)
            gn_edge<<<NEDGE / EM, 512, 0, stream>>>(
                tabP1, tabP2, ddegs, sdegs,
                wd + 2 * HD * HD, wd + 3 * HD * HD,
                eb16 + (size_t)d * HD, p_eb2 + (size_t)d * HD,
                p_elng + (size_t)d * HD, p_elnb + (size_t)d * HD, msg);
        else
            gn_edge<<<NEDGE / EM, 512, 0, stream>>>(
                P1, P2, dsorted, ssorted,
                wd + 2 * HD * HD, wd + 3 * HD * HD,
                eb16 + (size_t)d * HD, p_eb2 + (size_t)d * HD,
                p_elng + (size_t)d * HD, p_elnb + (size_t)d * HD, msg);
        if (d == 1) {
            const f16* wn = wbuf + (size_t)(d + 1) * 8 * HD * HD;
            gn_node<1, true, false, true><<<NTOT / 64, 256, 0, stream>>>(
                h16, msg, rowptr, deg, nullptr, nullptr, tabH,
                wd + 4 * HD * HD, wd + 5 * HD * HD, wd + 6 * HD * HD, wd + 7 * HD * HD,
                p_nb1 + (size_t)d * HD, p_nb2 + (size_t)d * HD,
                p_nlng + (size_t)d * HD, p_nlnb + (size_t)d * HD,
                wn + 0 * HD * HD, wn + 1 * HD * HD, P1, P2, nullptr, nullptr);
        } else if (d < DBLK - 1) {
            const f16* wn = wbuf + (size_t)(d + 1) * 8 * HD * HD;
            gn_node<1, true, false, false><<<NTOT / 64, 256, 0, stream>>>(
                h16, msg, rowptr, deg, nullptr, nullptr, nullptr,
                wd + 4 * HD * HD, wd + 5 * HD * HD, wd + 6 * HD * HD, wd + 7 * HD * HD,
                p_nb1 + (size_t)d * HD, p_nb2 + (size_t)d * HD,
                p_nlng + (size_t)d * HD, p_nlnb + (size_t)d * HD,
                wn + 0 * HD * HD, wn + 1 * HD * HD, P1, P2, nullptr, nullptr);
        } else {
            gn_node<1, false, true, false><<<NTOT / 64, 256, 0, stream>>>(
                h16, msg, rowptr, deg, nullptr, nullptr, nullptr,
                wd + 4 * HD * HD, wd + 5 * HD * HD, wd + 6 * HD * HD, wd + 7 * HD * HD,
                p_nb1 + (size_t)d * HD, p_nb2 + (size_t)d * HD,
                p_nlng + (size_t)d * HD, p_nlnb + (size_t)d * HD,
                wbuf, wbuf, P1, P2, dwt, uval);
        }
    }

    // ---- Decoder stage 2 only (stage 1 fused into the last node)
    dec_gather_out<<<(NMESH + 3) / 4, 256, 0, stream>>>(
        uval, mrow, mdeg, mslot, dec_cw1, dec_cb1, dec_cw2, dec_cb2, dec_cw3,
        (float*)d_out, NMESH);
}